// Round 8
// baseline (346.453 us; speedup 1.0000x reference)
//
#include <hip/hip_runtime.h>
#include <hip/hip_bf16.h>

#define N_NODES 50000
#define N_EDGES 1600000
#define NFEAT   512
#define HIDDEN  128
#define NCLASS  40

// 128 rows per bucket -> 391 buckets; bucket id = row >> 7
#define NBUCK 391
#define ROWS_PER_BUCKET 128
#define BUCK_PAD 4608             // mean 4096 + 8 sigma; padded bucket slots

#define W1T_BLOCKS 256
#define GEMM1_BLOCKS 391          // ceil(50000/128)
#define PART_T 8192
#define PART_BLOCKS 196           // ceil(1600000/8192)

// union LDS for the fused partition|gemm1 kernel:
// partition: sorted 65536 | cnt 1564 | cur 1564 | shift 1564 | ssc 2048
//          = 72276  (2 blocks/CU)
// gemm1:     As 8192 | Bs 8192 = 16384          -> max = 72276
#define FUSED_LDS 72276

typedef short short8 __attribute__((ext_vector_type(8)));
typedef float f32x4  __attribute__((ext_vector_type(4)));

// bf16 bits (RNE) from float
__device__ __forceinline__ unsigned short f2bu(float f) {
  __hip_bfloat16 h = __float2bfloat16(f);
  return *reinterpret_cast<unsigned short*>(&h);
}

// ---------------------------------------------------------------------------
// JAX threefry2x32, key (0,42), partitionable: bits[i] = o0^o1 of ctr (0,i).
// keep iff (bits>>31)==0.  (verified in earlier rounds)
// ---------------------------------------------------------------------------
__device__ __forceinline__ unsigned rotl32(unsigned x, int n) {
  return (x << n) | (x >> (32 - n));
}

__device__ __forceinline__ unsigned threefry_bits(unsigned x1) {
  unsigned x0 = 0u;
  const unsigned ks0 = 0u, ks1 = 42u, ks2 = 0x1BD11BDAu ^ 42u;
  x0 += ks0; x1 += ks1;
#define TFR(r) { x0 += x1; x1 = rotl32(x1, (r)); x1 ^= x0; }
  TFR(13) TFR(15) TFR(26) TFR(6)
  x0 += ks1; x1 += ks2 + 1u;
  TFR(17) TFR(29) TFR(16) TFR(24)
  x0 += ks2; x1 += ks0 + 2u;
  TFR(13) TFR(15) TFR(26) TFR(6)
  x0 += ks0; x1 += ks1 + 3u;
  TFR(17) TFR(29) TFR(16) TFR(24)
  x0 += ks1; x1 += ks2 + 4u;
  TFR(13) TFR(15) TFR(26) TFR(6)
  x0 += ks2; x1 += ks0 + 5u;
#undef TFR
  return x0 ^ x1;
}

// ---------------------------------------------------------------------------
// K1: W1 transpose (blocks 0..255) | gcur init to padded bucket bases
// (block 256). No histogram/scan needed with padded buckets.
// ---------------------------------------------------------------------------
__global__ __launch_bounds__(256) void init_w1t_kernel(
    const float* __restrict__ W1, unsigned short* __restrict__ W1T,
    int* __restrict__ gcur) {
  if (blockIdx.x < W1T_BLOCKS) {
    int id = blockIdx.x * 256 + threadIdx.x;  // 65536 exact
    int n = id & 127, k = id >> 7;
    W1T[n * NFEAT + k] = f2bu(W1[k * HIDDEN + n]);
  } else {
    int b = threadIdx.x;
    if (b < NBUCK) gcur[b] = b * BUCK_PAD;
    b += 256;
    if (b < NBUCK) gcur[b] = b * BUCK_PAD;
  }
}

// ---------------------------------------------------------------------------
// GEMM1 body (device fn): support = bf16(x) @ bf16(W1), fp32 acc, MFMA.
// Output now stored fp32 (removes bf16 unpack VALU from spmm1's gather).
// ---------------------------------------------------------------------------
__device__ __forceinline__ void gemm1_body(
    int bid, char* smem, const float* __restrict__ x,
    const unsigned short* __restrict__ W1T,
    float* __restrict__ support) {
  short8* As = (short8*)smem;           // 512 * 16 B, chunk = q*128 + row
  short8* Bs = (short8*)(smem + 8192);  // 512 * 16 B, chunk = q*128 + col
  const int t = threadIdx.x;
  const int lane = t & 63;
  const int w = t >> 6;
  const int quad = lane >> 4;
  const int l15 = lane & 15;
  const int node_base = bid * 128;
  const int mbase = (w >> 1) * 64;
  const int nbase = (w & 1) * 64;

  f32x4 acc[4][4] = {};

  for (int k0 = 0; k0 < NFEAT; k0 += 32) {
#pragma unroll
    for (int i = 0; i < 2; i++) {
      int lin = i * 256 + t;        // 0..511
      int n = lin >> 2, q = lin & 3;
      int row = node_base + n;
      if (row >= N_NODES) row = N_NODES - 1;
      const float* src = &x[(size_t)row * NFEAT + k0 + q * 8];
      float4 a = *(const float4*)src;
      float4 b = *(const float4*)(src + 4);
      short8 p;
      p[0] = (short)f2bu(a.x); p[1] = (short)f2bu(a.y);
      p[2] = (short)f2bu(a.z); p[3] = (short)f2bu(a.w);
      p[4] = (short)f2bu(b.x); p[5] = (short)f2bu(b.y);
      p[6] = (short)f2bu(b.z); p[7] = (short)f2bu(b.w);
      As[q * 128 + n] = p;
      Bs[q * 128 + n] = *(const short8*)&W1T[(size_t)n * NFEAT + k0 + q * 8];
    }
    __syncthreads();
    short8 af[4], bfr[4];
#pragma unroll
    for (int mt = 0; mt < 4; mt++)
      af[mt] = As[quad * 128 + mbase + mt * 16 + l15];
#pragma unroll
    for (int nt = 0; nt < 4; nt++)
      bfr[nt] = Bs[quad * 128 + nbase + nt * 16 + l15];
#pragma unroll
    for (int mt = 0; mt < 4; mt++)
#pragma unroll
      for (int nt = 0; nt < 4; nt++)
        acc[mt][nt] = __builtin_amdgcn_mfma_f32_16x16x32_bf16(
            af[mt], bfr[nt], acc[mt][nt], 0, 0, 0);
    __syncthreads();
  }

#pragma unroll
  for (int mt = 0; mt < 4; mt++)
#pragma unroll
    for (int nt = 0; nt < 4; nt++)
#pragma unroll
      for (int r = 0; r < 4; r++) {
        int row = node_base + mbase + mt * 16 + quad * 4 + r;
        int col = nbase + nt * 16 + l15;
        if (row < N_NODES)
          support[(size_t)row * HIDDEN + col] = acc[mt][nt][r];
      }
}

// ---------------------------------------------------------------------------
// Partition body: two-pass LDS counting sort of 8192 edges by bucket ->
// coalesced append into padded bucket regions of eb[] (runs of ~21 edges).
// Pass 1 counts (erow only); pass 2 re-reads from L2 and places records.
// Record: uint2 { col | bf16(val)<<16 , row }.
// ---------------------------------------------------------------------------
__device__ __forceinline__ void partition_body(
    int bid, char* smem, const int* __restrict__ erow,
    const int* __restrict__ ecol, const float* __restrict__ evals,
    int* __restrict__ gcur, uint2* __restrict__ eb) {
  uint2* sorted = (uint2*)smem;                    // 8192 * 8 B
  int* cnt   = (int*)(smem + 65536);               // 391 * 4
  int* cur   = (int*)(smem + 65536 + 1564);        // 391 * 4
  int* shift = (int*)(smem + 65536 + 3128);        // 391 * 4
  int* ssc   = (int*)(smem + 65536 + 4692);        // 512 * 4
  const int t = threadIdx.x;
  const int base = bid * PART_T;

  if (t < NBUCK) cnt[t] = 0;
  if (t + 256 < NBUCK) cnt[t + 256] = 0;
  __syncthreads();

  // pass 1: count rows per bucket
#pragma unroll 8
  for (int k = 0; k < 32; k++) {
    int idx = base + k * 256 + t;
    if (idx < N_EDGES) atomicAdd(&cnt[erow[idx] >> 7], 1);
  }
  __syncthreads();

  // inclusive scan of cnt (padded to 512)
  ssc[t] = (t < NBUCK) ? cnt[t] : 0;
  ssc[t + 256] = (t + 256 < NBUCK) ? cnt[t + 256] : 0;
  __syncthreads();
#pragma unroll
  for (int off = 1; off < 512; off <<= 1) {
    int v0 = (t >= off) ? ssc[t - off] : 0;
    int v1 = ssc[t + 256 - off];
    __syncthreads();
    ssc[t] += v0; ssc[t + 256] += v1;
    __syncthreads();
  }

  // init local cursors to exclusive base; claim global chunk
  for (int b = t; b < NBUCK; b += 256) {
    int c = cnt[b];
    int lb = ssc[b] - c;
    cur[b] = lb;
    if (c > 0) shift[b] = atomicAdd(&gcur[b], c) - lb;
  }
  __syncthreads();

  // pass 2: re-read (L2-hot) and place into sorted by bucket
#pragma unroll 8
  for (int k = 0; k < 32; k++) {
    int idx = base + k * 256 + t;
    if (idx < N_EDGES) {
      int r = erow[idx];
      unsigned rec = (unsigned)ecol[idx] | ((unsigned)f2bu(evals[idx]) << 16);
      int p = atomicAdd(&cur[r >> 7], 1);
      uint2 e; e.x = rec; e.y = (unsigned)r;
      sorted[p] = e;
    }
  }
  __syncthreads();

  // coalesced copy out: consecutive i share bucket in runs of ~21
  const int total = ssc[NBUCK - 1];
  for (int i = t; i < total; i += 256) {
    uint2 e = sorted[i];
    eb[shift[e.y >> 7] + i] = e;
  }
}

// ---------------------------------------------------------------------------
// K2 fused: partition (blocks 0..195) | GEMM1 (blocks 196..586).
// Union LDS buffer (72.3 KB) -> 2 blocks/CU (occupancy-insensitive phase).
// ---------------------------------------------------------------------------
__global__ __launch_bounds__(256) void part_gemm1_kernel(
    const int* __restrict__ erow, const int* __restrict__ ecol,
    const float* __restrict__ evals, int* __restrict__ gcur,
    uint2* __restrict__ eb, const float* __restrict__ x,
    const unsigned short* __restrict__ W1T,
    float* __restrict__ support) {
  __shared__ char smem[FUSED_LDS];
  if (blockIdx.x < PART_BLOCKS)
    partition_body(blockIdx.x, smem, erow, ecol, evals, gcur, eb);
  else
    gemm1_body(blockIdx.x - PART_BLOCKS, smem, x, W1T, support);
}

// ---------------------------------------------------------------------------
// K3: exact CSR from padded bucketed edges. Block b owns rows
// [b*128, b*128+128) and eb window [b*BUCK_PAD, gcur[b]). 128-bin LDS
// histogram -> scan -> rowptr/rowend; LDS-cursor scatter into csr (padded
// layout). All scattered writes land in a ~16 KB window.
// ---------------------------------------------------------------------------
__global__ __launch_bounds__(512) void csr_build_kernel(
    const uint2* __restrict__ eb, const int* __restrict__ gcur,
    unsigned* __restrict__ csr, int* __restrict__ rowptr,
    int* __restrict__ rowend) {
  __shared__ int cnt[ROWS_PER_BUCKET];
  __shared__ int sc[ROWS_PER_BUCKET];
  __shared__ int cur[ROWS_PER_BUCKET];
  const int t = threadIdx.x;
  const int b = blockIdx.x;
  if (t < ROWS_PER_BUCKET) cnt[t] = 0;
  __syncthreads();
  const int beg = b * BUCK_PAD;
  const int end = gcur[b];
  for (int j = beg + t; j < end; j += 512)
    atomicAdd(&cnt[eb[j].y & 127u], 1);
  __syncthreads();
  if (t < ROWS_PER_BUCKET) sc[t] = cnt[t];
  __syncthreads();
#pragma unroll
  for (int off = 1; off < ROWS_PER_BUCKET; off <<= 1) {
    int v = 0;
    if (t >= off && t < ROWS_PER_BUCKET) v = sc[t - off];
    __syncthreads();
    if (t < ROWS_PER_BUCKET) sc[t] += v;
    __syncthreads();
  }
  if (t < ROWS_PER_BUCKET) {
    int excl = sc[t] - cnt[t];
    cur[t] = excl;
    int row = b * ROWS_PER_BUCKET + t;
    if (row < N_NODES) {
      rowptr[row] = beg + excl;
      rowend[row] = beg + sc[t];
    }
  }
  __syncthreads();
  for (int j = beg + t; j < end; j += 512) {
    uint2 e = eb[j];
    int p = atomicAdd(&cur[e.y & 127u], 1);
    csr[beg + p] = e.x;
  }
}

// ---------------------------------------------------------------------------
// SpMM1 + GEMM2 fused: wave per row. Edge stream wave-uniform ->
// readfirstlane keeps col/val on the scalar pipe. Support is fp32 ->
// float2 gather, no unpack VALU; inner op = 2 FMA (SGPR val).
// Epilogue: +b1, relu, dropout -> fp32 h row in LDS; gemm2 tail reads
// Ws/hrow via imm-offset ds_read (1 FMA/iter VALU).
// ---------------------------------------------------------------------------
__global__ __launch_bounds__(256) void spmm1_fused(
    const unsigned* __restrict__ csr, const int* __restrict__ rowptr,
    const int* __restrict__ rowend,
    const float2* __restrict__ sup,  // support rows = 64 float2
    const float* __restrict__ b1, const float* __restrict__ W2,
    unsigned* __restrict__ h2u) {    // h2 rows = 20 uints (bf162)
  __shared__ float Ws[HIDDEN * NCLASS];   // 20 KB
  __shared__ float hrowf[4][HIDDEN];      // 2 KB
  const int t = threadIdx.x;
#pragma unroll
  for (int i = 0; i < 20; i++) Ws[i * 256 + t] = W2[i * 256 + t];
  __syncthreads();

  const int row = blockIdx.x * 4 + (t >> 6);
  const int wv = t >> 6;
  const int lane = t & 63;
  const int beg = __builtin_amdgcn_readfirstlane(rowptr[row]);
  const int end = __builtin_amdgcn_readfirstlane(rowend[row]);
  float ax = 0.f, ay = 0.f;
  int j = beg;
  for (; j + 15 < end; j += 16) {
    unsigned ps[16];
#pragma unroll
    for (int k = 0; k < 16; k++)
      ps[k] = __builtin_amdgcn_readfirstlane(csr[j + k]);
    float2 u[16];
#pragma unroll
    for (int k = 0; k < 16; k++)
      u[k] = sup[(size_t)(ps[k] & 0xffffu) * 64 + lane];
#pragma unroll
    for (int k = 0; k < 16; k++) {
      float v = __uint_as_float(ps[k] & 0xffff0000u);
      ax += v * u[k].x;
      ay += v * u[k].y;
    }
  }
  for (; j + 7 < end; j += 8) {
    unsigned ps[8];
#pragma unroll
    for (int k = 0; k < 8; k++)
      ps[k] = __builtin_amdgcn_readfirstlane(csr[j + k]);
    float2 u[8];
#pragma unroll
    for (int k = 0; k < 8; k++)
      u[k] = sup[(size_t)(ps[k] & 0xffffu) * 64 + lane];
#pragma unroll
    for (int k = 0; k < 8; k++) {
      float v = __uint_as_float(ps[k] & 0xffff0000u);
      ax += v * u[k].x;
      ay += v * u[k].y;
    }
  }
  for (; j + 1 < end; j += 2) {
    unsigned p0 = __builtin_amdgcn_readfirstlane(csr[j]);
    unsigned p1 = __builtin_amdgcn_readfirstlane(csr[j + 1]);
    float2 u0 = sup[(size_t)(p0 & 0xffffu) * 64 + lane];
    float2 u1 = sup[(size_t)(p1 & 0xffffu) * 64 + lane];
    float v0 = __uint_as_float(p0 & 0xffff0000u);
    float v1 = __uint_as_float(p1 & 0xffff0000u);
    ax += v0 * u0.x + v1 * u1.x;
    ay += v0 * u0.y + v1 * u1.y;
  }
  if (j < end) {
    unsigned p0 = __builtin_amdgcn_readfirstlane(csr[j]);
    float2 u0 = sup[(size_t)(p0 & 0xffffu) * 64 + lane];
    float v0 = __uint_as_float(p0 & 0xffff0000u);
    ax += v0 * u0.x;
    ay += v0 * u0.y;
  }
  const unsigned i0 = (unsigned)row * HIDDEN + lane * 2;
  float vx = fmaxf(ax + b1[lane * 2], 0.f);
  float vy = fmaxf(ay + b1[lane * 2 + 1], 0.f);
  vx = (threefry_bits(i0) >> 31) ? 0.f : 2.f * vx;
  vy = (threefry_bits(i0 + 1) >> 31) ? 0.f : 2.f * vy;
  hrowf[wv][lane * 2] = vx;
  hrowf[wv][lane * 2 + 1] = vy;
  __syncthreads();

  // gemm2 tail: lane c (<40) computes h2[row][c] = sum_k h[k] * W2[k][c]
  float accv = 0.f;
  if (lane < NCLASS) {
#pragma unroll
    for (int i = 0; i < HIDDEN; i++)
      accv += hrowf[wv][i] * Ws[i * NCLASS + lane];
    float other = __shfl_xor(accv, 1);
    if (!(lane & 1))
      h2u[(unsigned)row * 20 + (lane >> 1)] =
          (unsigned)f2bu(accv) | ((unsigned)f2bu(other) << 16);
  }
}

// ---------------------------------------------------------------------------
// SpMM2 fused: wave per row, half-split x 4-unroll = 8 edges in flight.
// (readfirstlane NOT applicable: j differs between lane-halves.)
// ---------------------------------------------------------------------------
__global__ __launch_bounds__(256) void spmm2_fused(
    const unsigned* __restrict__ csr, const int* __restrict__ rowptr,
    const int* __restrict__ rowend,
    const unsigned* __restrict__ h2u,  // rows = 20 uints
    const float* __restrict__ b2, float* __restrict__ out) {
  const int row = blockIdx.x * 4 + (threadIdx.x >> 6);
  const int lane = threadIdx.x & 63;
  const int half = lane >> 5;
  const int il = lane & 31;
  const unsigned ilc = (il < 20) ? (unsigned)il : 19u;
  const int beg = rowptr[row], end = rowend[row];
  float ax = 0.f, ay = 0.f;
  int j = beg + half;
  for (; j + 6 < end; j += 8) {
    unsigned p[4], u[4];
#pragma unroll
    for (int k = 0; k < 4; k++) p[k] = csr[j + 2 * k];
#pragma unroll
    for (int k = 0; k < 4; k++) u[k] = h2u[(p[k] & 0xffffu) * 20 + ilc];
#pragma unroll
    for (int k = 0; k < 4; k++) {
      float v = __uint_as_float(p[k] & 0xffff0000u);
      ax += v * __uint_as_float(u[k] << 16);
      ay += v * __uint_as_float(u[k] & 0xffff0000u);
    }
  }
  for (; j + 2 < end; j += 4) {
    unsigned p0 = csr[j];
    unsigned p1 = csr[j + 2];
    unsigned u0 = h2u[(p0 & 0xffffu) * 20 + ilc];
    unsigned u1 = h2u[(p1 & 0xffffu) * 20 + ilc];
    float v0 = __uint_as_float(p0 & 0xffff0000u);
    float v1 = __uint_as_float(p1 & 0xffff0000u);
    ax += v0 * __uint_as_float(u0 << 16) + v1 * __uint_as_float(u1 << 16);
    ay += v0 * __uint_as_float(u0 & 0xffff0000u) +
          v1 * __uint_as_float(u1 & 0xffff0000u);
  }
  for (; j < end; j += 2) {
    unsigned p0 = csr[j];
    unsigned u0 = h2u[(p0 & 0xffffu) * 20 + ilc];
    float v0 = __uint_as_float(p0 & 0xffff0000u);
    ax += v0 * __uint_as_float(u0 << 16);
    ay += v0 * __uint_as_float(u0 & 0xffff0000u);
  }
  ax += __shfl_xor(ax, 32);
  ay += __shfl_xor(ay, 32);
  if (half == 0 && il < 20) {
    float2 r;
    r.x = fmaxf(ax + b2[il * 2], 0.f);
    r.y = fmaxf(ay + b2[il * 2 + 1], 0.f);
    *(float2*)&out[(unsigned)row * NCLASS + il * 2] = r;
  }
}

extern "C" void kernel_launch(void* const* d_in, const int* in_sizes, int n_in,
                              void* d_out, int out_size, void* d_ws,
                              size_t ws_size, hipStream_t stream) {
  const float* x     = (const float*)d_in[0];
  const int*   erow  = (const int*)d_in[1];
  const int*   ecol  = (const int*)d_in[2];
  const float* evals = (const float*)d_in[3];
  const float* W1    = (const float*)d_in[4];
  const float* b1    = (const float*)d_in[5];
  const float* W2    = (const float*)d_in[6];
  const float* b2    = (const float*)d_in[7];
  float* out = (float*)d_out;

  // ws layout (bytes):
  //   support fp32 25.6M @ 0
  //   eb (padded, 391*4608*8 = 14,413,824) @ 25,600,000
  //   h2 4M @ 40,013,824 | W1T 128K @ 44,013,824
  //   csr (padded, 7,206,912) @ 44,144,896
  //   rowptr 200K @ 51,351,808 | rowend 200K @ 51,551,808
  //   gcur 1.6K @ 51,751,808        (~51.8 MB total)
  char* base = (char*)d_ws;
  float*          support = (float*)base;
  uint2*          eb  = (uint2*)(base + 25600000);
  unsigned*       h2  = (unsigned*)(base + 40013824);
  unsigned short* W1T = (unsigned short*)(base + 44013824);
  unsigned*       csr = (unsigned*)(base + 44144896);
  int* rowptr = (int*)(base + 51351808);
  int* rowend = (int*)(base + 51551808);
  int* gcur   = (int*)(base + 51751808);

  init_w1t_kernel<<<W1T_BLOCKS + 1, 256, 0, stream>>>(W1, W1T, gcur);
  part_gemm1_kernel<<<PART_BLOCKS + GEMM1_BLOCKS, 256, 0, stream>>>(
      erow, ecol, evals, gcur, eb, x, W1T, support);
  csr_build_kernel<<<NBUCK, 512, 0, stream>>>(eb, gcur, csr, rowptr, rowend);
  spmm1_fused<<<N_NODES / 4, 256, 0, stream>>>(
      csr, rowptr, rowend, (const float2*)support, b1, W2, h2);
  spmm2_fused<<<N_NODES / 4, 256, 0, stream>>>(csr, rowptr, rowend,
                                               (const unsigned*)h2, b2, out);
}

// Round 9
// 311.850 us; speedup vs baseline: 1.1110x; 1.1110x over previous
//
#include <hip/hip_runtime.h>
#include <hip/hip_bf16.h>

#define N_NODES 50000
#define N_EDGES 1600000
#define NFEAT   512
#define HIDDEN  128
#define NCLASS  40

// 128 rows per bucket -> 391 buckets; bucket id = row >> 7
#define NBUCK 391
#define ROWS_PER_BUCKET 128
#define BUCK_PAD 4608             // mean 4096 + 8 sigma; padded bucket slots

#define W1T_BLOCKS 256
#define GEMM1_BLOCKS 391          // ceil(50000/128)
#define PART_T 8192
#define PART_BLOCKS 196           // ceil(1600000/8192)

// union LDS for the fused partition|gemm1 kernel:
// partition: sorted 65536 | cnt 1564 | cur 1564 | shift 1564 | ssc 2048
//          = 72276  (2 blocks/CU)
// gemm1:     As 8192 | Bs 8192 = 16384          -> max = 72276
#define FUSED_LDS 72276

typedef short short8 __attribute__((ext_vector_type(8)));
typedef float f32x4  __attribute__((ext_vector_type(4)));

// bf16 bits (RNE) from float
__device__ __forceinline__ unsigned short f2bu(float f) {
  __hip_bfloat16 h = __float2bfloat16(f);
  return *reinterpret_cast<unsigned short*>(&h);
}

// ---------------------------------------------------------------------------
// JAX threefry2x32, key (0,42), partitionable: bits[i] = o0^o1 of ctr (0,i).
// keep iff (bits>>31)==0.  (verified in earlier rounds)
// ---------------------------------------------------------------------------
__device__ __forceinline__ unsigned rotl32(unsigned x, int n) {
  return (x << n) | (x >> (32 - n));
}

__device__ __forceinline__ unsigned threefry_bits(unsigned x1) {
  unsigned x0 = 0u;
  const unsigned ks0 = 0u, ks1 = 42u, ks2 = 0x1BD11BDAu ^ 42u;
  x0 += ks0; x1 += ks1;
#define TFR(r) { x0 += x1; x1 = rotl32(x1, (r)); x1 ^= x0; }
  TFR(13) TFR(15) TFR(26) TFR(6)
  x0 += ks1; x1 += ks2 + 1u;
  TFR(17) TFR(29) TFR(16) TFR(24)
  x0 += ks2; x1 += ks0 + 2u;
  TFR(13) TFR(15) TFR(26) TFR(6)
  x0 += ks0; x1 += ks1 + 3u;
  TFR(17) TFR(29) TFR(16) TFR(24)
  x0 += ks1; x1 += ks2 + 4u;
  TFR(13) TFR(15) TFR(26) TFR(6)
  x0 += ks2; x1 += ks0 + 5u;
#undef TFR
  return x0 ^ x1;
}

// ---------------------------------------------------------------------------
// K1: W1 transpose (blocks 0..255) | gcur init to padded bucket bases
// (block 256). No histogram/scan needed with padded buckets.
// ---------------------------------------------------------------------------
__global__ __launch_bounds__(256) void init_w1t_kernel(
    const float* __restrict__ W1, unsigned short* __restrict__ W1T,
    int* __restrict__ gcur) {
  if (blockIdx.x < W1T_BLOCKS) {
    int id = blockIdx.x * 256 + threadIdx.x;  // 65536 exact
    int n = id & 127, k = id >> 7;
    W1T[n * NFEAT + k] = f2bu(W1[k * HIDDEN + n]);
  } else {
    int b = threadIdx.x;
    if (b < NBUCK) gcur[b] = b * BUCK_PAD;
    b += 256;
    if (b < NBUCK) gcur[b] = b * BUCK_PAD;
  }
}

// ---------------------------------------------------------------------------
// GEMM1 body (device fn): support = bf16(x) @ bf16(W1), fp32 acc, MFMA.
// Output bf16 (r8's fp32 doubled the gather footprint -> 346 MB fetch;
// bf16 keeps the random-gather working set at 12.8 MB / 149 MB fetch).
// ---------------------------------------------------------------------------
__device__ __forceinline__ void gemm1_body(
    int bid, char* smem, const float* __restrict__ x,
    const unsigned short* __restrict__ W1T,
    unsigned short* __restrict__ support) {
  short8* As = (short8*)smem;           // 512 * 16 B, chunk = q*128 + row
  short8* Bs = (short8*)(smem + 8192);  // 512 * 16 B, chunk = q*128 + col
  const int t = threadIdx.x;
  const int lane = t & 63;
  const int w = t >> 6;
  const int quad = lane >> 4;
  const int l15 = lane & 15;
  const int node_base = bid * 128;
  const int mbase = (w >> 1) * 64;
  const int nbase = (w & 1) * 64;

  f32x4 acc[4][4] = {};

  for (int k0 = 0; k0 < NFEAT; k0 += 32) {
#pragma unroll
    for (int i = 0; i < 2; i++) {
      int lin = i * 256 + t;        // 0..511
      int n = lin >> 2, q = lin & 3;
      int row = node_base + n;
      if (row >= N_NODES) row = N_NODES - 1;
      const float* src = &x[(size_t)row * NFEAT + k0 + q * 8];
      float4 a = *(const float4*)src;
      float4 b = *(const float4*)(src + 4);
      short8 p;
      p[0] = (short)f2bu(a.x); p[1] = (short)f2bu(a.y);
      p[2] = (short)f2bu(a.z); p[3] = (short)f2bu(a.w);
      p[4] = (short)f2bu(b.x); p[5] = (short)f2bu(b.y);
      p[6] = (short)f2bu(b.z); p[7] = (short)f2bu(b.w);
      As[q * 128 + n] = p;
      Bs[q * 128 + n] = *(const short8*)&W1T[(size_t)n * NFEAT + k0 + q * 8];
    }
    __syncthreads();
    short8 af[4], bfr[4];
#pragma unroll
    for (int mt = 0; mt < 4; mt++)
      af[mt] = As[quad * 128 + mbase + mt * 16 + l15];
#pragma unroll
    for (int nt = 0; nt < 4; nt++)
      bfr[nt] = Bs[quad * 128 + nbase + nt * 16 + l15];
#pragma unroll
    for (int mt = 0; mt < 4; mt++)
#pragma unroll
      for (int nt = 0; nt < 4; nt++)
        acc[mt][nt] = __builtin_amdgcn_mfma_f32_16x16x32_bf16(
            af[mt], bfr[nt], acc[mt][nt], 0, 0, 0);
    __syncthreads();
  }

#pragma unroll
  for (int mt = 0; mt < 4; mt++)
#pragma unroll
    for (int nt = 0; nt < 4; nt++)
#pragma unroll
      for (int r = 0; r < 4; r++) {
        int row = node_base + mbase + mt * 16 + quad * 4 + r;
        int col = nbase + nt * 16 + l15;
        if (row < N_NODES)
          support[(size_t)row * HIDDEN + col] = f2bu(acc[mt][nt][r]);
      }
}

// ---------------------------------------------------------------------------
// Partition body: two-pass LDS counting sort of 8192 edges by bucket ->
// coalesced append into padded bucket regions of eb[] (runs of ~21 edges).
// Pass 1 counts (erow only); pass 2 re-reads from L2 and places records.
// Record: uint2 { col | bf16(val)<<16 , row }.
// ---------------------------------------------------------------------------
__device__ __forceinline__ void partition_body(
    int bid, char* smem, const int* __restrict__ erow,
    const int* __restrict__ ecol, const float* __restrict__ evals,
    int* __restrict__ gcur, uint2* __restrict__ eb) {
  uint2* sorted = (uint2*)smem;                    // 8192 * 8 B
  int* cnt   = (int*)(smem + 65536);               // 391 * 4
  int* cur   = (int*)(smem + 65536 + 1564);        // 391 * 4
  int* shift = (int*)(smem + 65536 + 3128);        // 391 * 4
  int* ssc   = (int*)(smem + 65536 + 4692);        // 512 * 4
  const int t = threadIdx.x;
  const int base = bid * PART_T;

  if (t < NBUCK) cnt[t] = 0;
  if (t + 256 < NBUCK) cnt[t + 256] = 0;
  __syncthreads();

  // pass 1: count rows per bucket
#pragma unroll 8
  for (int k = 0; k < 32; k++) {
    int idx = base + k * 256 + t;
    if (idx < N_EDGES) atomicAdd(&cnt[erow[idx] >> 7], 1);
  }
  __syncthreads();

  // inclusive scan of cnt (padded to 512)
  ssc[t] = (t < NBUCK) ? cnt[t] : 0;
  ssc[t + 256] = (t + 256 < NBUCK) ? cnt[t + 256] : 0;
  __syncthreads();
#pragma unroll
  for (int off = 1; off < 512; off <<= 1) {
    int v0 = (t >= off) ? ssc[t - off] : 0;
    int v1 = ssc[t + 256 - off];
    __syncthreads();
    ssc[t] += v0; ssc[t + 256] += v1;
    __syncthreads();
  }

  // init local cursors to exclusive base; claim global chunk
  for (int b = t; b < NBUCK; b += 256) {
    int c = cnt[b];
    int lb = ssc[b] - c;
    cur[b] = lb;
    if (c > 0) shift[b] = atomicAdd(&gcur[b], c) - lb;
  }
  __syncthreads();

  // pass 2: re-read (L2-hot) and place into sorted by bucket
#pragma unroll 8
  for (int k = 0; k < 32; k++) {
    int idx = base + k * 256 + t;
    if (idx < N_EDGES) {
      int r = erow[idx];
      unsigned rec = (unsigned)ecol[idx] | ((unsigned)f2bu(evals[idx]) << 16);
      int p = atomicAdd(&cur[r >> 7], 1);
      uint2 e; e.x = rec; e.y = (unsigned)r;
      sorted[p] = e;
    }
  }
  __syncthreads();

  // coalesced copy out: consecutive i share bucket in runs of ~21
  const int total = ssc[NBUCK - 1];
  for (int i = t; i < total; i += 256) {
    uint2 e = sorted[i];
    eb[shift[e.y >> 7] + i] = e;
  }
}

// ---------------------------------------------------------------------------
// K2 fused: partition (blocks 0..195) | GEMM1 (blocks 196..586).
// Union LDS buffer (72.3 KB) -> 2 blocks/CU (occupancy-insensitive phase).
// ---------------------------------------------------------------------------
__global__ __launch_bounds__(256) void part_gemm1_kernel(
    const int* __restrict__ erow, const int* __restrict__ ecol,
    const float* __restrict__ evals, int* __restrict__ gcur,
    uint2* __restrict__ eb, const float* __restrict__ x,
    const unsigned short* __restrict__ W1T,
    unsigned short* __restrict__ support) {
  __shared__ char smem[FUSED_LDS];
  if (blockIdx.x < PART_BLOCKS)
    partition_body(blockIdx.x, smem, erow, ecol, evals, gcur, eb);
  else
    gemm1_body(blockIdx.x - PART_BLOCKS, smem, x, W1T, support);
}

// ---------------------------------------------------------------------------
// K3: exact CSR from padded bucketed edges. Block b owns rows
// [b*128, b*128+128) and eb window [b*BUCK_PAD, gcur[b]). 128-bin LDS
// histogram -> scan -> rowptr/rowend; LDS-cursor scatter into csr (padded
// layout). All scattered writes land in a ~16 KB window.
// ---------------------------------------------------------------------------
__global__ __launch_bounds__(512) void csr_build_kernel(
    const uint2* __restrict__ eb, const int* __restrict__ gcur,
    unsigned* __restrict__ csr, int* __restrict__ rowptr,
    int* __restrict__ rowend) {
  __shared__ int cnt[ROWS_PER_BUCKET];
  __shared__ int sc[ROWS_PER_BUCKET];
  __shared__ int cur[ROWS_PER_BUCKET];
  const int t = threadIdx.x;
  const int b = blockIdx.x;
  if (t < ROWS_PER_BUCKET) cnt[t] = 0;
  __syncthreads();
  const int beg = b * BUCK_PAD;
  const int end = gcur[b];
  for (int j = beg + t; j < end; j += 512)
    atomicAdd(&cnt[eb[j].y & 127u], 1);
  __syncthreads();
  if (t < ROWS_PER_BUCKET) sc[t] = cnt[t];
  __syncthreads();
#pragma unroll
  for (int off = 1; off < ROWS_PER_BUCKET; off <<= 1) {
    int v = 0;
    if (t >= off && t < ROWS_PER_BUCKET) v = sc[t - off];
    __syncthreads();
    if (t < ROWS_PER_BUCKET) sc[t] += v;
    __syncthreads();
  }
  if (t < ROWS_PER_BUCKET) {
    int excl = sc[t] - cnt[t];
    cur[t] = excl;
    int row = b * ROWS_PER_BUCKET + t;
    if (row < N_NODES) {
      rowptr[row] = beg + excl;
      rowend[row] = beg + sc[t];
    }
  }
  __syncthreads();
  for (int j = beg + t; j < end; j += 512) {
    uint2 e = eb[j];
    int p = atomicAdd(&cur[e.y & 127u], 1);
    csr[beg + p] = e.x;
  }
}

// ---------------------------------------------------------------------------
// SpMM1 + GEMM2 fused: wave per row. Edge stream wave-uniform ->
// readfirstlane keeps col/val on the scalar pipe (SGPR val src0 in FMA).
// bf16 support gather (256 B/row, 12.8 MB working set); 2 unpack VALU/edge.
// Epilogue: +b1, relu, dropout -> fp32 h row in LDS; gemm2 tail = 128
// FMA/lane from LDS (r8's lean form).
// ---------------------------------------------------------------------------
__global__ __launch_bounds__(256) void spmm1_fused(
    const unsigned* __restrict__ csr, const int* __restrict__ rowptr,
    const int* __restrict__ rowend,
    const unsigned* __restrict__ sup,  // support rows = 64 uints (bf16x2)
    const float* __restrict__ b1, const float* __restrict__ W2,
    unsigned* __restrict__ h2u) {    // h2 rows = 20 uints (bf162)
  __shared__ float Ws[HIDDEN * NCLASS];   // 20 KB
  __shared__ float hrowf[4][HIDDEN];      // 2 KB
  const int t = threadIdx.x;
#pragma unroll
  for (int i = 0; i < 20; i++) Ws[i * 256 + t] = W2[i * 256 + t];
  __syncthreads();

  const int row = blockIdx.x * 4 + (t >> 6);
  const int wv = t >> 6;
  const int lane = t & 63;
  const int beg = __builtin_amdgcn_readfirstlane(rowptr[row]);
  const int end = __builtin_amdgcn_readfirstlane(rowend[row]);
  float ax = 0.f, ay = 0.f;
  int j = beg;
  for (; j + 15 < end; j += 16) {
    unsigned ps[16];
#pragma unroll
    for (int k = 0; k < 16; k++)
      ps[k] = __builtin_amdgcn_readfirstlane(csr[j + k]);
    unsigned u[16];
#pragma unroll
    for (int k = 0; k < 16; k++)
      u[k] = sup[(size_t)(ps[k] & 0xffffu) * 64 + lane];
#pragma unroll
    for (int k = 0; k < 16; k++) {
      float v = __uint_as_float(ps[k] & 0xffff0000u);
      ax += v * __uint_as_float(u[k] << 16);
      ay += v * __uint_as_float(u[k] & 0xffff0000u);
    }
  }
  for (; j + 7 < end; j += 8) {
    unsigned ps[8];
#pragma unroll
    for (int k = 0; k < 8; k++)
      ps[k] = __builtin_amdgcn_readfirstlane(csr[j + k]);
    unsigned u[8];
#pragma unroll
    for (int k = 0; k < 8; k++)
      u[k] = sup[(size_t)(ps[k] & 0xffffu) * 64 + lane];
#pragma unroll
    for (int k = 0; k < 8; k++) {
      float v = __uint_as_float(ps[k] & 0xffff0000u);
      ax += v * __uint_as_float(u[k] << 16);
      ay += v * __uint_as_float(u[k] & 0xffff0000u);
    }
  }
  for (; j + 1 < end; j += 2) {
    unsigned p0 = __builtin_amdgcn_readfirstlane(csr[j]);
    unsigned p1 = __builtin_amdgcn_readfirstlane(csr[j + 1]);
    unsigned u0 = sup[(size_t)(p0 & 0xffffu) * 64 + lane];
    unsigned u1 = sup[(size_t)(p1 & 0xffffu) * 64 + lane];
    float v0 = __uint_as_float(p0 & 0xffff0000u);
    float v1 = __uint_as_float(p1 & 0xffff0000u);
    ax += v0 * __uint_as_float(u0 << 16) + v1 * __uint_as_float(u1 << 16);
    ay += v0 * __uint_as_float(u0 & 0xffff0000u) +
          v1 * __uint_as_float(u1 & 0xffff0000u);
  }
  if (j < end) {
    unsigned p0 = __builtin_amdgcn_readfirstlane(csr[j]);
    unsigned u0 = sup[(size_t)(p0 & 0xffffu) * 64 + lane];
    float v0 = __uint_as_float(p0 & 0xffff0000u);
    ax += v0 * __uint_as_float(u0 << 16);
    ay += v0 * __uint_as_float(u0 & 0xffff0000u);
  }
  const unsigned i0 = (unsigned)row * HIDDEN + lane * 2;
  float vx = fmaxf(ax + b1[lane * 2], 0.f);
  float vy = fmaxf(ay + b1[lane * 2 + 1], 0.f);
  vx = (threefry_bits(i0) >> 31) ? 0.f : 2.f * vx;
  vy = (threefry_bits(i0 + 1) >> 31) ? 0.f : 2.f * vy;
  hrowf[wv][lane * 2] = __uint_as_float((unsigned)f2bu(vx) << 16);
  hrowf[wv][lane * 2 + 1] = __uint_as_float((unsigned)f2bu(vy) << 16);
  __syncthreads();

  // gemm2 tail: lane c (<40) computes h2[row][c] = sum_k h[k] * W2[k][c]
  float accv = 0.f;
  if (lane < NCLASS) {
#pragma unroll
    for (int i = 0; i < HIDDEN; i++)
      accv += hrowf[wv][i] * Ws[i * NCLASS + lane];
    float other = __shfl_xor(accv, 1);
    if (!(lane & 1))
      h2u[(unsigned)row * 20 + (lane >> 1)] =
          (unsigned)f2bu(accv) | ((unsigned)f2bu(other) << 16);
  }
}

// ---------------------------------------------------------------------------
// SpMM2 fused: wave per row, half-split x 4-unroll = 8 edges in flight.
// (readfirstlane NOT applicable: j differs between lane-halves.)
// ---------------------------------------------------------------------------
__global__ __launch_bounds__(256) void spmm2_fused(
    const unsigned* __restrict__ csr, const int* __restrict__ rowptr,
    const int* __restrict__ rowend,
    const unsigned* __restrict__ h2u,  // rows = 20 uints
    const float* __restrict__ b2, float* __restrict__ out) {
  const int row = blockIdx.x * 4 + (threadIdx.x >> 6);
  const int lane = threadIdx.x & 63;
  const int half = lane >> 5;
  const int il = lane & 31;
  const unsigned ilc = (il < 20) ? (unsigned)il : 19u;
  const int beg = rowptr[row], end = rowend[row];
  float ax = 0.f, ay = 0.f;
  int j = beg + half;
  for (; j + 6 < end; j += 8) {
    unsigned p[4], u[4];
#pragma unroll
    for (int k = 0; k < 4; k++) p[k] = csr[j + 2 * k];
#pragma unroll
    for (int k = 0; k < 4; k++) u[k] = h2u[(p[k] & 0xffffu) * 20 + ilc];
#pragma unroll
    for (int k = 0; k < 4; k++) {
      float v = __uint_as_float(p[k] & 0xffff0000u);
      ax += v * __uint_as_float(u[k] << 16);
      ay += v * __uint_as_float(u[k] & 0xffff0000u);
    }
  }
  for (; j + 2 < end; j += 4) {
    unsigned p0 = csr[j];
    unsigned p1 = csr[j + 2];
    unsigned u0 = h2u[(p0 & 0xffffu) * 20 + ilc];
    unsigned u1 = h2u[(p1 & 0xffffu) * 20 + ilc];
    float v0 = __uint_as_float(p0 & 0xffff0000u);
    float v1 = __uint_as_float(p1 & 0xffff0000u);
    ax += v0 * __uint_as_float(u0 << 16) + v1 * __uint_as_float(u1 << 16);
    ay += v0 * __uint_as_float(u0 & 0xffff0000u) +
          v1 * __uint_as_float(u1 & 0xffff0000u);
  }
  for (; j < end; j += 2) {
    unsigned p0 = csr[j];
    unsigned u0 = h2u[(p0 & 0xffffu) * 20 + ilc];
    float v0 = __uint_as_float(p0 & 0xffff0000u);
    ax += v0 * __uint_as_float(u0 << 16);
    ay += v0 * __uint_as_float(u0 & 0xffff0000u);
  }
  ax += __shfl_xor(ax, 32);
  ay += __shfl_xor(ay, 32);
  if (half == 0 && il < 20) {
    float2 r;
    r.x = fmaxf(ax + b2[il * 2], 0.f);
    r.y = fmaxf(ay + b2[il * 2 + 1], 0.f);
    *(float2*)&out[(unsigned)row * NCLASS + il * 2] = r;
  }
}

extern "C" void kernel_launch(void* const* d_in, const int* in_sizes, int n_in,
                              void* d_out, int out_size, void* d_ws,
                              size_t ws_size, hipStream_t stream) {
  const float* x     = (const float*)d_in[0];
  const int*   erow  = (const int*)d_in[1];
  const int*   ecol  = (const int*)d_in[2];
  const float* evals = (const float*)d_in[3];
  const float* W1    = (const float*)d_in[4];
  const float* b1    = (const float*)d_in[5];
  const float* W2    = (const float*)d_in[6];
  const float* b2    = (const float*)d_in[7];
  float* out = (float*)d_out;

  // ws layout (bytes):
  //   support bf16 12.8M @ 0
  //   eb (padded, 391*4608*8 = 14,413,824) @ 12,800,000
  //   h2 4M @ 27,213,824 | W1T 128K @ 31,213,824
  //   csr (padded, 7,206,912) @ 31,344,896
  //   rowptr 200K @ 38,551,808 | rowend 200K @ 38,751,808
  //   gcur 1.6K @ 38,951,808        (~39 MB total)
  char* base = (char*)d_ws;
  unsigned short* support = (unsigned short*)base;
  uint2*          eb  = (uint2*)(base + 12800000);
  unsigned*       h2  = (unsigned*)(base + 27213824);
  unsigned short* W1T = (unsigned short*)(base + 31213824);
  unsigned*       csr = (unsigned*)(base + 31344896);
  int* rowptr = (int*)(base + 38551808);
  int* rowend = (int*)(base + 38751808);
  int* gcur   = (int*)(base + 38951808);

  init_w1t_kernel<<<W1T_BLOCKS + 1, 256, 0, stream>>>(W1, W1T, gcur);
  part_gemm1_kernel<<<PART_BLOCKS + GEMM1_BLOCKS, 256, 0, stream>>>(
      erow, ecol, evals, gcur, eb, x, W1T, support);
  csr_build_kernel<<<NBUCK, 512, 0, stream>>>(eb, gcur, csr, rowptr, rowend);
  spmm1_fused<<<N_NODES / 4, 256, 0, stream>>>(
      csr, rowptr, rowend, (const unsigned*)support, b1, W2, h2);
  spmm2_fused<<<N_NODES / 4, 256, 0, stream>>>(csr, rowptr, rowend,
                                               (const unsigned*)h2, b2, out);
}